// Round 1
// baseline (276.586 us; speedup 1.0000x reference)
//
#include <hip/hip_runtime.h>

// FMFMNeuron: leaky-integrate-and-fire scan.
//   cur[t,b]  = s[t,b,0]*w1 + s[t,b,1]*w2        (s in {0,1} -> products exact in f32)
//   reset     = (mem_prev > 1.0)                  (== spk[t-1], reuse it)
//   mem       = ((0.95f*mem_prev) + cur) - reset  (match numpy left-to-right, NO fma)
//   spk[t,b]  = (mem > 1.0f) ? 1.0f : 0.0f        ((mem-1>0) == (mem>1) exactly in f32)
//
// Parallel over B=4096 neurons only (scan is sequential in T). One thread per
// neuron, float2 loads (8B/lane, 512B/wave coalesced), unroll for load overlap.

#define T_STEPS 4096
#define B_NEUR  4096

__global__ __launch_bounds__(64) void fmfm_scan_kernel(
    const float2* __restrict__ sp,   // [T, B] of float2 (the trailing dim 2)
    const float*  __restrict__ W,    // [w1, w2]
    float*        __restrict__ out)  // [T, B]
{
    const int b = blockIdx.x * 64 + threadIdx.x;   // 0..4095
    const float w1 = W[0];
    const float w2 = W[1];

    const float2* p = sp  + b;
    float*        q = out + b;

    float mem = 0.0f;
    float rst = 0.0f;   // reset at step t == spike at step t-1

    #pragma unroll 8
    for (int t = 0; t < T_STEPS; ++t) {
        float2 s = p[(size_t)t * B_NEUR];
        // cur: products are exact (s in {0,1}); single rounding on the add.
        float cur = __fadd_rn(__fmul_rn(s.x, w1), __fmul_rn(s.y, w2));
        // mem update: strict left-to-right f32, no contraction.
        float m  = __fsub_rn(__fadd_rn(__fmul_rn(0.95f, mem), cur), rst);
        float spk = (m > 1.0f) ? 1.0f : 0.0f;
        q[(size_t)t * B_NEUR] = spk;
        mem = m;
        rst = spk;
    }
}

extern "C" void kernel_launch(void* const* d_in, const int* in_sizes, int n_in,
                              void* d_out, int out_size, void* d_ws, size_t ws_size,
                              hipStream_t stream) {
    const float2* sp = (const float2*)d_in[0];   // spike_seq [T,B,2] f32
    const float*  W  = (const float*)d_in[1];    // [1,2] f32
    float*        out = (float*)d_out;           // [T,B,1] f32

    fmfm_scan_kernel<<<dim3(B_NEUR / 64), dim3(64), 0, stream>>>(sp, W, out);
}

// Round 3
// 129.534 us; speedup vs baseline: 2.1352x; 2.1352x over previous
//
#include <hip/hip_runtime.h>
#include <stdint.h>

// FMFMNeuron LIF scan, 2-phase:
//  Phase A (64 waves, latency-pipelined): stream 134MB spikes with a 4-deep x
//    16-step rotating register buffer (64 loads in flight/wave ~ vmcnt cap),
//    run the exact sequential scan, emit 1-bit spikes (2MB) to d_ws.
//  Phase B (2048 waves): expand 2MB bits -> 67MB f32 output at write BW.
//    Grid = 128 words * 1024 uint4-groups / 256 = 512 blocks (r2 bug: had 128).
//
// Scan math is bit-exact vs numpy (validated absmax=0 in round 1):
//   cur = fadd(fmul(s.x,w1), fmul(s.y,w2))     (products exact, s in {0,1})
//   m   = fsub(fadd(fmul(0.95f,mem), cur), rst)  strict left-to-right, no FMA
//   spk = (m > 1.0f); rst_next = spk             ((m-1>0) == (m>1) in f32 here)

#define T_STEPS 4096
#define B_NEUR  4096
#define U 16                   // steps per pipeline body
#define NB (T_STEPS / U)       // 256 bodies
#define NWORDS (T_STEPS / 32)  // 128 packed words per neuron

__global__ __launch_bounds__(64) void fmfm_scan_pack(
    const float2* __restrict__ sp,      // [T][B] float2
    const float*  __restrict__ W,       // [w1, w2]
    uint32_t*     __restrict__ bits_out)// [T/32][B]
{
    const int b = blockIdx.x * 64 + threadIdx.x;   // 0..4095
    const float w1 = W[0];
    const float w2 = W[1];
    const float2* p = sp + b;

    // 4-deep rotating register buffers, statically indexed (no scratch).
    float2 buf0[U], buf1[U], buf2[U], buf3[U];

#define LOADB(BUF, BODY_EXPR)                                             \
    {                                                                     \
        int _tb = (BODY_EXPR);                                            \
        if (_tb > NB - 1) _tb = NB - 1;     /* tail clamp (dup is ok) */  \
        const size_t _base = (size_t)_tb * U * B_NEUR;                    \
        _Pragma("unroll")                                                 \
        for (int _i = 0; _i < U; ++_i)                                    \
            BUF[_i] = p[_base + (size_t)_i * B_NEUR];                     \
    }

#define PROC(BUF, HALF)                                                   \
    {                                                                     \
        _Pragma("unroll")                                                 \
        for (int _i = 0; _i < U; ++_i) {                                  \
            float2 _s = BUF[_i];                                          \
            float _cur = __fadd_rn(__fmul_rn(_s.x, w1),                   \
                                   __fmul_rn(_s.y, w2));                  \
            float _m = __fsub_rn(__fadd_rn(__fmul_rn(0.95f, mem), _cur),  \
                                 rst);                                    \
            uint32_t _sb = (_m > 1.0f) ? 1u : 0u;                         \
            bits |= _sb << ((HALF) * U + _i);                             \
            rst = _sb ? 1.0f : 0.0f;                                      \
            mem = _m;                                                     \
        }                                                                 \
    }

    // prologue: fill pipeline with bodies 0..3 (64 loads in flight)
    LOADB(buf0, 0)
    LOADB(buf1, 1)
    LOADB(buf2, 2)
    LOADB(buf3, 3)

    float mem = 0.0f;
    float rst = 0.0f;
    uint32_t bits = 0;

    for (int ob = 0; ob < NB; ob += 4) {
        PROC(buf0, 0)
        LOADB(buf0, ob + 4)
        PROC(buf1, 1)
        bits_out[(size_t)(ob >> 1) * B_NEUR + b] = bits;   // t = ob*16..+31
        bits = 0;
        LOADB(buf1, ob + 5)
        PROC(buf2, 0)
        LOADB(buf2, ob + 6)
        PROC(buf3, 1)
        bits_out[(size_t)((ob >> 1) + 1) * B_NEUR + b] = bits;
        bits = 0;
        LOADB(buf3, ob + 7)
    }
#undef LOADB
#undef PROC
}

__global__ __launch_bounds__(256) void fmfm_expand(
    const uint32_t* __restrict__ bits,  // [T/32][B]
    float*          __restrict__ out)   // [T][B]
{
    const int tid = blockIdx.x * 256 + threadIdx.x;  // 0..131071
    const int b4  = tid & 1023;                      // group of 4 neurons
    const int w   = tid >> 10;                       // word row 0..127
    const uint4 wv = *reinterpret_cast<const uint4*>(
        bits + (size_t)w * B_NEUR + (size_t)b4 * 4);
    float4* o = reinterpret_cast<float4*>(
        out + (size_t)w * 32 * B_NEUR + (size_t)b4 * 4);
    #pragma unroll
    for (int j = 0; j < 32; ++j) {
        float4 v;
        v.x = ((wv.x >> j) & 1u) ? 1.0f : 0.0f;
        v.y = ((wv.y >> j) & 1u) ? 1.0f : 0.0f;
        v.z = ((wv.z >> j) & 1u) ? 1.0f : 0.0f;
        v.w = ((wv.w >> j) & 1u) ? 1.0f : 0.0f;
        o[(size_t)j * (B_NEUR / 4)] = v;
    }
}

// Round-1 proven fused fallback (used only if ws_size < 2MB).
__global__ __launch_bounds__(64) void fmfm_scan_fused(
    const float2* __restrict__ sp, const float* __restrict__ W,
    float* __restrict__ out)
{
    const int b = blockIdx.x * 64 + threadIdx.x;
    const float w1 = W[0];
    const float w2 = W[1];
    const float2* p = sp + b;
    float* q = out + b;
    float mem = 0.0f, rst = 0.0f;
    #pragma unroll 8
    for (int t = 0; t < T_STEPS; ++t) {
        float2 s = p[(size_t)t * B_NEUR];
        float cur = __fadd_rn(__fmul_rn(s.x, w1), __fmul_rn(s.y, w2));
        float m = __fsub_rn(__fadd_rn(__fmul_rn(0.95f, mem), cur), rst);
        float spk = (m > 1.0f) ? 1.0f : 0.0f;
        q[(size_t)t * B_NEUR] = spk;
        mem = m;
        rst = spk;
    }
}

extern "C" void kernel_launch(void* const* d_in, const int* in_sizes, int n_in,
                              void* d_out, int out_size, void* d_ws, size_t ws_size,
                              hipStream_t stream) {
    const float2* sp  = (const float2*)d_in[0];  // spike_seq [T,B,2] f32
    const float*  W   = (const float*)d_in[1];   // [1,2] f32
    float*        out = (float*)d_out;           // [T,B,1] f32

    const size_t bits_bytes = (size_t)NWORDS * B_NEUR * sizeof(uint32_t); // 2MB
    if (ws_size < bits_bytes) {
        fmfm_scan_fused<<<dim3(B_NEUR / 64), dim3(64), 0, stream>>>(sp, W, out);
        return;
    }
    uint32_t* bits = (uint32_t*)d_ws;

    fmfm_scan_pack<<<dim3(B_NEUR / 64), dim3(64), 0, stream>>>(sp, W, bits);
    fmfm_expand<<<dim3((NWORDS * (B_NEUR / 4)) / 256 /* = 512 */),
                  dim3(256), 0, stream>>>(bits, out);
}